// Round 1
// baseline (230.639 us; speedup 1.0000x reference)
//
#include <hip/hip_runtime.h>
#include <hip/hip_bf16.h>

#define VOCABN 50000
#define BN 128
#define CN 5
#define HN 50
#define LN 32
#define DN 300
#define DP 320     // padded K
#define KNN 20

typedef __bf16 bf16x8 __attribute__((ext_vector_type(8)));
typedef float  f32x4  __attribute__((ext_vector_type(4)));

#if __has_builtin(__builtin_amdgcn_exp2f)
#define FEXP2 __builtin_amdgcn_exp2f
#else
#define FEXP2 exp2f
#endif
#if __has_builtin(__builtin_amdgcn_logf)
#define FLOG2 __builtin_amdgcn_logf
#else
#define FLOG2 log2f
#endif

#define LOG2E 1.4426950408889634f
#define LN2F  0.6931471805599453f

// ---------------- kernel 1: normalize vocab -> bf16 table [VOCAB][DP] ----------------
__global__ __launch_bounds__(256) void knorm_embed(const float* __restrict__ emb,
                                                   __hip_bfloat162* __restrict__ tab2) {
    const int v = blockIdx.x;
    const float* row = emb + (size_t)v * DN;
    const int t = threadIdx.x;

    float x0 = (t < DN) ? row[t] : 0.f;
    float x1 = (t + 256 < DN) ? row[t + 256] : 0.f;
    float ss = x0 * x0 + x1 * x1;
    #pragma unroll
    for (int off = 32; off; off >>= 1) ss += __shfl_xor(ss, off);
    __shared__ float red[4];
    if ((t & 63) == 0) red[t >> 6] = ss;
    __syncthreads();
    float tot = red[0] + red[1] + red[2] + red[3];
    float scale = 1.0f / fmaxf(sqrtf(tot), 1e-8f);

    if (t < DP / 2) {                 // 160 bf16 pairs per row
        int e = t * 2;
        float a = (e < DN) ? row[e] * scale : 0.f;
        float b = (e + 1 < DN) ? row[e + 1] * scale : 0.f;
        __hip_bfloat162 p;
        p.x = __float2bfloat16(a);
        p.y = __float2bfloat16(b);
        tab2[(size_t)v * (DP / 2) + t] = p;
    }
}

// ---------------- kernel 2: fused sim(MFMA) + kernel pooling + score partial ----------------
__device__ inline bf16x8 ldfrag(const ushort* buf, int row, int kc, int lane) {
    // buf is [rows][64] bf16, 128B rows, 16B chunks XOR-swizzled by (row&7)
    int cM = kc * 4 + (lane >> 4);
    int off = row * 128 + (((cM ^ (row & 7))) << 4);
    int4 raw = *(const int4*)((const char*)buf + off);
    return __builtin_bit_cast(bf16x8, raw);
}

__global__ __launch_bounds__(320) void knrm_fused(const int* __restrict__ cand,
                                                  const int* __restrict__ clik,
                                                  const ushort* __restrict__ tab,   // bf16 bits
                                                  const float* __restrict__ ltr_w,
                                                  float* __restrict__ score) {
    __shared__ __align__(16) ushort Abuf[160 * 64];   // 20 KB
    __shared__ __align__(16) ushort Bbuf[32 * 64];    // 4 KB
    __shared__ float simbuf[160 * 33];                // 21 KB, pad 33
    __shared__ int   tokA[160];
    __shared__ int   tokB[32];
    __shared__ float red[5][5];

    const int t    = threadIdx.x;
    const int lane = t & 63;
    const int w    = t >> 6;          // wave 0..4
    const int bid  = blockIdx.x;
    const int b    = bid / 10;        // 10 h-chunks of 5
    const int hc   = bid % 10;

    if (t < 160) tokA[t] = cand[b * (CN * LN) + t];

    // pooling constants: fixed kernel index per thread
    const int kq = t % 20;
    const int r0 = t / 20;            // 0..15
    const float mu  = 0.1f * (float)kq - 0.9f;
    const float sig = (kq == 19) ? 0.001f : 0.1f;
    const float ak  = sqrtf(LOG2E / (2.0f * sig * sig));
    const float bk  = -mu * ak;

    float accs[5] = {0.f, 0.f, 0.f, 0.f, 0.f};

    const int m15 = lane & 15;
    const int rowA0 = w * 32 + m15;   // A rows for this wave's two M-tiles

    for (int h = hc * 5; h < hc * 5 + 5; ++h) {
        __syncthreads();                                  // prev iter done with tokB/simbuf
        if (t < 32) tokB[t] = clik[b * (HN * LN) + h * LN + t];

        f32x4 acc[2][2];
        #pragma unroll
        for (int mt = 0; mt < 2; ++mt)
            #pragma unroll
            for (int nt = 0; nt < 2; ++nt)
                acc[mt][nt] = (f32x4){0.f, 0.f, 0.f, 0.f};

        for (int kk = 0; kk < 5; ++kk) {                  // K slices of 64
            __syncthreads();                              // buffers free to overwrite
            // stage A: 160 rows x 8 chunks(16B) = 1280 chunks, 4 per thread
            #pragma unroll
            for (int it = 0; it < 4; ++it) {
                int cid = it * 320 + t;
                int row = cid >> 3, cs = cid & 7;
                int csrc = cs ^ (row & 7);
                const int4* src = (const int4*)((const char*)tab +
                    (size_t)tokA[row] * (DP * 2) + kk * 128 + csrc * 16);
                *(int4*)((char*)Abuf + row * 128 + cs * 16) = *src;
            }
            // stage B: 32 x 8 = 256 chunks
            if (t < 256) {
                int row = t >> 3, cs = t & 7;
                int csrc = cs ^ (row & 7);
                const int4* src = (const int4*)((const char*)tab +
                    (size_t)tokB[row] * (DP * 2) + kk * 128 + csrc * 16);
                *(int4*)((char*)Bbuf + row * 128 + cs * 16) = *src;
            }
            __syncthreads();
            #pragma unroll
            for (int kc = 0; kc < 2; ++kc) {              // two K=32 sub-steps
                bf16x8 a0 = ldfrag(Abuf, rowA0,      kc, lane);
                bf16x8 a1 = ldfrag(Abuf, rowA0 + 16, kc, lane);
                bf16x8 b0 = ldfrag(Bbuf, m15,        kc, lane);
                bf16x8 b1 = ldfrag(Bbuf, m15 + 16,   kc, lane);
                acc[0][0] = __builtin_amdgcn_mfma_f32_16x16x32_bf16(a0, b0, acc[0][0], 0, 0, 0);
                acc[0][1] = __builtin_amdgcn_mfma_f32_16x16x32_bf16(a0, b1, acc[0][1], 0, 0, 0);
                acc[1][0] = __builtin_amdgcn_mfma_f32_16x16x32_bf16(a1, b0, acc[1][0], 0, 0, 0);
                acc[1][1] = __builtin_amdgcn_mfma_f32_16x16x32_bf16(a1, b1, acc[1][1], 0, 0, 0);
            }
        }
        // write sim tile: C/D layout col=lane&15, row=(lane>>4)*4+reg  [m89-verified]
        #pragma unroll
        for (int mt = 0; mt < 2; ++mt)
            #pragma unroll
            for (int nt = 0; nt < 2; ++nt)
                #pragma unroll
                for (int r = 0; r < 4; ++r) {
                    int row = w * 32 + mt * 16 + ((lane >> 4) << 2) + r;
                    int col = nt * 16 + m15;
                    simbuf[row * 33 + col] = acc[mt][nt][r];
                }
        __syncthreads();

        // pooling: thread owns kernel kq, rows it*16+r0
        const float wlog = ltr_w[h * KNN + kq] * LN2F;
        #pragma unroll
        for (int it = 0; it < 10; ++it) {
            int row = it * 16 + r0;
            const float* srow = &simbuf[row * 33];
            float p0 = 0.f, p1 = 0.f;
            #pragma unroll
            for (int j = 0; j < 32; j += 2) {
                float d0 = fmaf(srow[j], ak, bk);
                float d1 = fmaf(srow[j + 1], ak, bk);
                p0 += FEXP2(-(d0 * d0));
                p1 += FEXP2(-(d1 * d1));
            }
            float pooled = fmaxf(p0 + p1, 1e-10f);
            accs[it >> 1] += FLOG2(pooled) * wlog;        // it>>1 == row/32 == c (compile-time)
        }
    }

    // block reduction of per-thread score partials (5 c-values)
    #pragma unroll
    for (int c = 0; c < 5; ++c) {
        float v = accs[c];
        #pragma unroll
        for (int off = 32; off; off >>= 1) v += __shfl_xor(v, off);
        accs[c] = v;
    }
    if (lane == 0)
        #pragma unroll
        for (int c = 0; c < 5; ++c) red[w][c] = accs[c];
    __syncthreads();
    if (t < 5) {
        float s = red[0][t] + red[1][t] + red[2][t] + red[3][t] + red[4][t];
        atomicAdd(&score[b * CN + t], s);
    }
}

// ---------------- kernel 3: log_softmax over C (ltr_b cancels) ----------------
__global__ __launch_bounds__(128) void knrm_final(const float* __restrict__ score,
                                                  float* __restrict__ out) {
    int b = threadIdx.x;
    if (b < BN) {
        float s[CN];
        float m = -1e30f;
        #pragma unroll
        for (int c = 0; c < CN; ++c) { s[c] = score[b * CN + c]; m = fmaxf(m, s[c]); }
        float sum = 0.f;
        #pragma unroll
        for (int c = 0; c < CN; ++c) sum += FEXP2((s[c] - m) * LOG2E);
        float lse = m + FLOG2(sum) * LN2F;
        #pragma unroll
        for (int c = 0; c < CN; ++c) out[b * CN + c] = s[c] - lse;
    }
}

extern "C" void kernel_launch(void* const* d_in, const int* in_sizes, int n_in,
                              void* d_out, int out_size, void* d_ws, size_t ws_size,
                              hipStream_t stream) {
    const int*   cand  = (const int*)d_in[0];   // [B,C,L]
    const int*   clik  = (const int*)d_in[1];   // [B,H,L]
    const float* emb   = (const float*)d_in[2]; // [VOCAB,D]
    const float* ltr_w = (const float*)d_in[3]; // [1,H*KN]
    // d_in[4] = ltr_b (cancels in log_softmax)
    float* out = (float*)d_out;

    __hip_bfloat162* tab2 = (__hip_bfloat162*)d_ws;
    ushort* tab = (ushort*)d_ws;                                  // bf16 bits view
    float* score = (float*)((char*)d_ws + (size_t)VOCABN * DP * 2); // 32 MB offset

    hipMemsetAsync(score, 0, BN * CN * sizeof(float), stream);
    knorm_embed<<<VOCABN, 256, 0, stream>>>(emb, tab2);
    knrm_fused<<<BN * 10, 320, 0, stream>>>(cand, clik, tab, ltr_w, score);
    knrm_final<<<1, 128, 0, stream>>>(score, out);
}